// Round 4
// baseline (37.791 us; speedup 1.0000x reference)
//
#include <hip/hip_runtime.h>
#include <math.h>

#define N_KEYS 8192
#define DIM    1024
#define BQ     64
#define TOPK   4
#define HD     512
#define KSPLIT 2
#define KSLICE (DIM / KSPLIT)   // 512 dims per block
#define NBLK   32               // keys per block
#define KC     128              // dims per LDS chunk
#define NCHUNK (KSLICE / KC)    // 4

typedef _Float16 half8 __attribute__((ext_vector_type(8)));
typedef _Float16 half4 __attribute__((ext_vector_type(4)));
typedef float    f32x4 __attribute__((ext_vector_type(4)));

__device__ __forceinline__ bool better(float av, int ai, float bv, int bi) {
    return (av > bv) || (av == bv && ai < bi);
}

__device__ __forceinline__ void ce(float& av, int& ai, float& bv, int& bi) {
    if (!better(av, ai, bv, bi)) {
        float tv = av; av = bv; bv = tv;
        int   ti = ai; ai = bi; bi = ti;
    }
}

__device__ __forceinline__ void merge_shfl(float v[4], int ix[4], int off) {
    float pv[4]; int pi[4];
    #pragma unroll
    for (int r = 0; r < 4; ++r) {
        pv[r] = __shfl_xor(v[r], off);
        pi[r] = __shfl_xor(ix[r], off);
    }
    float nv[4]; int ni[4];
    #pragma unroll
    for (int r = 0; r < 4; ++r) {
        bool ta = better(v[r], ix[r], pv[3 - r], pi[3 - r]);
        nv[r] = ta ? v[r]  : pv[3 - r];
        ni[r] = ta ? ix[r] : pi[3 - r];
    }
    ce(nv[0], ni[0], nv[2], ni[2]);
    ce(nv[1], ni[1], nv[3], ni[3]);
    ce(nv[0], ni[0], nv[1], ni[1]);
    ce(nv[2], ni[2], nv[3], ni[3]);
    #pragma unroll
    for (int r = 0; r < 4; ++r) { v[r] = nv[r]; ix[r] = ni[r]; }
}

// ---------------- prep: eq = exp(q) split into hi/lo f16 ----------------
__global__ __launch_bounds__(256) void prep_q(const float4* __restrict__ q4,
                                              _Float16* __restrict__ eqh,
                                              _Float16* __restrict__ eql) {
    int i = blockIdx.x * 256 + threadIdx.x;    // 64 blocks -> 16384 float4
    float4 v = q4[i];
    float e0 = expf(v.x), e1 = expf(v.y), e2 = expf(v.z), e3 = expf(v.w);
    half4 h, l;
    h[0] = (_Float16)e0; h[1] = (_Float16)e1; h[2] = (_Float16)e2; h[3] = (_Float16)e3;
    l[0] = (_Float16)(e0 - (float)h[0]); l[1] = (_Float16)(e1 - (float)h[1]);
    l[2] = (_Float16)(e2 - (float)h[2]); l[3] = (_Float16)(e3 - (float)h[3]);
    *(half4*)&eqh[i * 4] = h;
    *(half4*)&eql[i * 4] = l;
}

// stage one float4 of exp(key) into swizzled hi/lo f16 LDS
__device__ __forceinline__ void stage_write(_Float16* BhB, _Float16* BlB,
                                            int key, int c4, float4 v) {
    float e0 = expf(v.x), e1 = expf(v.y), e2 = expf(v.z), e3 = expf(v.w);
    half4 h, l;
    h[0] = (_Float16)e0; h[1] = (_Float16)e1; h[2] = (_Float16)e2; h[3] = (_Float16)e3;
    l[0] = (_Float16)(e0 - (float)h[0]); l[1] = (_Float16)(e1 - (float)h[1]);
    l[2] = (_Float16)(e2 - (float)h[2]); l[3] = (_Float16)(e3 - (float)h[3]);
    int g   = (c4 >> 1) ^ (key & 7);                 // XOR swizzle on 16B groups
    int idx = key * KC + g * 8 + (c4 & 1) * 4;
    *(half4*)(BhB + idx) = h;
    *(half4*)(BlB + idx) = l;
}

// ---------------- scores: split-f16 3-MFMA emulated-f32 GEMM ----------------
// part[slice][b][key] = sum_{d in slice} exp(q[b,d]) * exp(k[key,d])
__global__ __launch_bounds__(512, 4) void scores_mfma(
        const _Float16* __restrict__ eqh, const _Float16* __restrict__ eql,
        const float* __restrict__ keys, float* __restrict__ part) {
    __shared__ _Float16 Bh[2][NBLK * KC];    // 8 KB per buffer
    __shared__ _Float16 Bl[2][NBLK * KC];

    const int t    = threadIdx.x;
    const int lane = t & 63, w = t >> 6;     // 8 waves
    const int wm   = w >> 1, wn = w & 1;     // 4(M) x 2(N)
    const int l15  = lane & 15, l4 = lane >> 4;
    const int i0    = blockIdx.x * NBLK;
    const int dbase = blockIdx.y * KSLICE;

    // staging map: thread covers float4 indices t and t+512 of the 32x128 chunk
    const int key0 = t >> 5;           // 0..15
    const int c4s  = t & 31;           // 0..31

    const float* kb = keys + (size_t)i0 * DIM + dbase + 4 * c4s;

    // prologue: load + write chunk 0
    float4 p0 = *(const float4*)(kb + (size_t)key0 * DIM);
    float4 p1 = *(const float4*)(kb + (size_t)(key0 + 16) * DIM);
    stage_write(Bh[0], Bl[0], key0,      c4s, p0);
    stage_write(Bh[0], Bl[0], key0 + 16, c4s, p1);
    __syncthreads();

    f32x4 acc = {0.f, 0.f, 0.f, 0.f};
    const int arow = 16 * wm + l15;
    const int kk   = 16 * wn + l15;

    for (int c = 0; c < NCHUNK; ++c) {
        const int buf = c & 1;
        // issue next chunk's global loads early
        if (c + 1 < NCHUNK) {
            const float* kbc = kb + (c + 1) * KC;
            p0 = *(const float4*)(kbc + (size_t)key0 * DIM);
            p1 = *(const float4*)(kbc + (size_t)(key0 + 16) * DIM);
        }
        #pragma unroll
        for (int ks = 0; ks < KC / 32; ++ks) {
            const _Float16* ap = &eqh[(size_t)arow * DIM + dbase + c * KC + ks * 32 + l4 * 8];
            half8 Ah = *(const half8*)ap;
            half8 Al = *(const half8*)&eql[(size_t)arow * DIM + dbase + c * KC + ks * 32 + l4 * 8];
            int g = ((ks * 4 + l4) ^ (kk & 7)) * 8;
            half8 bh = *(const half8*)&Bh[buf][kk * KC + g];
            half8 bl = *(const half8*)&Bl[buf][kk * KC + g];
            acc = __builtin_amdgcn_mfma_f32_16x16x32_f16(Ah, bh, acc, 0, 0, 0);
            acc = __builtin_amdgcn_mfma_f32_16x16x32_f16(Ah, bl, acc, 0, 0, 0);
            acc = __builtin_amdgcn_mfma_f32_16x16x32_f16(Al, bh, acc, 0, 0, 0);
        }
        if (c + 1 < NCHUNK) {
            stage_write(Bh[buf ^ 1], Bl[buf ^ 1], key0,      c4s, p0);
            stage_write(Bh[buf ^ 1], Bl[buf ^ 1], key0 + 16, c4s, p1);
        }
        __syncthreads();
    }

    // epilogue: C layout col=lane&15, row=(lane>>4)*4+reg
    float* pb = part + (size_t)blockIdx.y * (BQ * N_KEYS);
    #pragma unroll
    for (int r = 0; r < 4; ++r) {
        int row = 16 * wm + l4 * 4 + r;
        int col = i0 + 16 * wn + l15;
        pb[(size_t)row * N_KEYS + col] = acc[r];
    }
}

// ---------------- topk partial: per (b, quarter-of-keys) sorted top-4 ----------------
template<int KS>
__global__ __launch_bounds__(1024) void topk_partial(const float* __restrict__ part,
                                                     float* __restrict__ cv,
                                                     int* __restrict__ ci) {
    const int b     = blockIdx.x >> 2;
    const int chunk = blockIdx.x & 3;
    const int t     = threadIdx.x;
    const int lane  = t & 63, wid = t >> 6;

    __shared__ float sv[16][4];
    __shared__ int   si[16][4];

    float v[4]  = {-INFINITY, -INFINITY, -INFINITY, -INFINITY};
    int   ix[4] = {0x7fffffff, 0x7fffffff, 0x7fffffff, 0x7fffffff};

    const float* pb = part + (size_t)b * N_KEYS;
    #pragma unroll
    for (int r = 0; r < 2; ++r) {
        int i = chunk * 2048 + t + r * 1024;
        float s = 0.f;
        #pragma unroll
        for (int sl = 0; sl < KS; ++sl)
            s += pb[(size_t)sl * (BQ * N_KEYS) + i];
        if (better(s, i, v[3], ix[3])) {
            v[3] = s; ix[3] = i;
            #pragma unroll
            for (int p = 3; p > 0; --p) {
                if (better(v[p], ix[p], v[p - 1], ix[p - 1])) {
                    float tv = v[p]; v[p] = v[p-1]; v[p-1] = tv;
                    int   ti = ix[p]; ix[p] = ix[p-1]; ix[p-1] = ti;
                }
            }
        }
    }
    merge_shfl(v, ix, 1);  merge_shfl(v, ix, 2);  merge_shfl(v, ix, 4);
    merge_shfl(v, ix, 8);  merge_shfl(v, ix, 16); merge_shfl(v, ix, 32);

    if (lane == 0) {
        #pragma unroll
        for (int r = 0; r < 4; ++r) { sv[wid][r] = v[r]; si[wid][r] = ix[r]; }
    }
    __syncthreads();

    if (wid == 0) {
        float mv[4]; int mi[4];
        if (lane < 16) {
            #pragma unroll
            for (int r = 0; r < 4; ++r) { mv[r] = sv[lane][r]; mi[r] = si[lane][r]; }
        } else {
            #pragma unroll
            for (int r = 0; r < 4; ++r) { mv[r] = -INFINITY; mi[r] = 0x7fffffff; }
        }
        merge_shfl(mv, mi, 1); merge_shfl(mv, mi, 2);
        merge_shfl(mv, mi, 4); merge_shfl(mv, mi, 8);
        if (lane == 0) {
            #pragma unroll
            for (int r = 0; r < 4; ++r) {
                cv[blockIdx.x * 4 + r] = mv[r];
                ci[blockIdx.x * 4 + r] = mi[r];
            }
        }
    }
}

// ---------------- finalize: merge 4 chunk-lists, softmax, gather ----------------
__global__ __launch_bounds__(64) void finalize_kernel(const float* __restrict__ cv,
                                                      const int* __restrict__ ci,
                                                      const float* __restrict__ theta,
                                                      const float* __restrict__ mag,
                                                      float* __restrict__ out) {
    const int b    = blockIdx.x;
    const int lane = threadIdx.x;

    __shared__ float fw[4];
    __shared__ int   fi[4];

    float v[4]  = {-INFINITY, -INFINITY, -INFINITY, -INFINITY};
    int   ix[4] = {0x7fffffff, 0x7fffffff, 0x7fffffff, 0x7fffffff};
    if (lane < 4) {
        #pragma unroll
        for (int r = 0; r < 4; ++r) {
            v[r]  = cv[(b * 4 + lane) * 4 + r];
            ix[r] = ci[(b * 4 + lane) * 4 + r];
        }
    }
    merge_shfl(v, ix, 1); merge_shfl(v, ix, 2);

    if (lane == 0) {
        float ssum = v[0] + v[1] + v[2] + v[3];   // positive exp-sums
        #pragma unroll
        for (int r = 0; r < 4; ++r) { fw[r] = v[r] / ssum; fi[r] = ix[r]; }
    }
    __syncthreads();

    const float4* th4 = (const float4*)theta;
    float4* out4 = (float4*)out;
    #pragma unroll
    for (int r = 0; r < 8; ++r) {
        int l = lane + r * 64;
        int j = l >> 7, c4 = l & 127;
        out4[((size_t)b * TOPK + j) * (HD / 4) + c4] = th4[(size_t)fi[j] * (HD / 4) + c4];
    }
    if (lane < TOPK) {
        out[(size_t)BQ * TOPK * HD + b * TOPK + lane]             = mag[fi[lane]];
        out[(size_t)BQ * TOPK * HD + BQ * TOPK + b * TOPK + lane] = fw[lane];
    }
}

extern "C" void kernel_launch(void* const* d_in, const int* in_sizes, int n_in,
                              void* d_out, int out_size, void* d_ws, size_t ws_size,
                              hipStream_t stream) {
    const float* q     = (const float*)d_in[0];
    const float* keys  = (const float*)d_in[1];
    const float* theta = (const float*)d_in[2];
    const float* mag   = (const float*)d_in[3];
    float* out = (float*)d_out;

    float*    part = (float*)d_ws;                              // 2 * 64*8192 f32 = 4 MB
    _Float16* eqh  = (_Float16*)(part + (size_t)KSPLIT * BQ * N_KEYS);
    _Float16* eql  = eqh + (size_t)BQ * DIM;
    float*    cv   = (float*)(eql + (size_t)BQ * DIM);
    int*      ci   = (int*)(cv + BQ * 4 * TOPK);

    prep_q<<<BQ * DIM / 4 / 256, 256, 0, stream>>>((const float4*)q, eqh, eql);
    scores_mfma<<<dim3(N_KEYS / NBLK, KSPLIT), 512, 0, stream>>>(eqh, eql, keys, part);
    topk_partial<KSPLIT><<<BQ * 4, 1024, 0, stream>>>(part, cv, ci);
    finalize_kernel<<<BQ, 64, 0, stream>>>(cv, ci, theta, mag, out);
}